// Round 9
// baseline (605.700 us; speedup 1.0000x reference)
//
#include <hip/hip_runtime.h>
#include <math.h>

#define BB 32
#define DKK 64
#define NN 2048
#define MM 2048
#define MSPLIT 4
#define RQ 2            // 16-row query tiles per wave (32 queries/wave)

typedef __attribute__((ext_vector_type(8))) _Float16 hfrag8;  // 8 fp16 (4 VGPRs)
typedef __attribute__((ext_vector_type(4))) float facc4;      // 4 f32
typedef __attribute__((ext_vector_type(2))) float f32x2;      // packed f32 pair

// ---------------------------------------------------------------------------
// Pre-pass: KE [B][64][M] f32 -> KH fragment-ready fp16
// frag layout per (b, mt16, dchunk): 64 lanes x 8 el;
//   element (lane,j) = K[d = 32*dchunk + 8*(lane>>4) + j][m = 16*mt16 + (lane&15)]
// ---------------------------------------------------------------------------
__global__ __launch_bounds__(256) void prep_k(const float* __restrict__ KE,
                                              hfrag8* __restrict__ KH)
{
    const int b = blockIdx.y, mb = blockIdx.x;
    const int t = threadIdx.x;
    const int seg = t >> 6, lane = t & 63;
    __shared__ float T[64][65];

    const float* src = KE + (size_t)b * 64 * MM + mb * 64;
#pragma unroll
    for (int i = 0; i < 16; ++i) {
        int d = i * 4 + seg;
        T[d][lane] = src[(size_t)d * MM + lane];
    }
    __syncthreads();

    const int lq = lane >> 4, lm = lane & 15;
#pragma unroll
    for (int p = 0; p < 2; ++p) {
        hfrag8 f;
#pragma unroll
        for (int j = 0; j < 8; ++j)
            f[j] = (_Float16)T[32 * p + 8 * lq + j][16 * seg + lm];
        KH[((size_t)(b * 128 + mb * 4 + seg) * 2 + p) * 64 + lane] = f;
    }
}

// ---------------------------------------------------------------------------
// Main flash kernel: 4 independent waves/block (no barriers, no LDS).
// Wave owns 32 queries; M split 4 ways. Single-pass fp16 MFMA.
// Q pre-scaled by log2(e)/8 so p = v_exp_f32(score) directly.
// Softmax accumulate as 2x v_pk_fma_f32 per element.
// PART[b][ms][n][4] = {l, a0, a1, a2}
// ---------------------------------------------------------------------------
__global__ __launch_bounds__(256, 4) void attn_main(
    const float* __restrict__ AE,   // action_embedding [B,64,N]
    const float* __restrict__ ANP,  // anchor_points    [B,3,M]
    const hfrag8* __restrict__ KH,
    float* __restrict__ PART)
{
    const int t = threadIdx.x;
    const int w = t >> 6, l = t & 63;
    const int ms = blockIdx.x, b = blockIdx.z;
    const int nw = blockIdx.y * 4 + w;   // 0..63
    const int n0 = nw * 32;
    const int lq = l >> 4, lm = l & 15;

    // ---- gather Q fragments once, prescaled, fp16 ----
    const float SC = 0.125f * 1.44269504088896340736f;
    hfrag8 qf[RQ][2];
    const float* qbase = AE + (size_t)b * 64 * NN + n0 + lm;
#pragma unroll
    for (int r = 0; r < RQ; ++r) {
#pragma unroll
        for (int c = 0; c < 2; ++c) {
            hfrag8 f;
#pragma unroll
            for (int j = 0; j < 8; ++j) {
                int d = 32 * c + 8 * lq + j;
                f[j] = (_Float16)(qbase[(size_t)d * NN + 16 * r] * SC);
            }
            qf[r][c] = f;
        }
    }

    // accA = {accL, a0}, accB = {a1, a2} per (r,e)
    f32x2 accA[RQ][4] = {}, accB[RQ][4] = {};

    const hfrag8* kb = KH + (size_t)b * 128 * 2 * 64;
    const float* vb = ANP + (size_t)b * 3 * MM;
    const int mt0 = ms * 32;   // 32 16-key tiles per (b,ms)

    // prologue: tile 0 into registers
    size_t kidx = ((size_t)mt0 * 2) * 64 + l;
    hfrag8 k0 = kb[kidx], k1 = kb[kidx + 64];
    int m = mt0 * 16 + lm;
    f32x2 mA = {1.f, vb[m]}, mB = {vb[MM + m], vb[2 * MM + m]};

    for (int mt = 0; mt < 32; ++mt) {
        const int mtn = (mt + 1) & 31;   // wrap: last prefetch re-reads tile 0 (L2 hit)
        size_t kidx2 = ((size_t)(mt0 + mtn) * 2) * 64 + l;
        hfrag8 nk0 = kb[kidx2], nk1 = kb[kidx2 + 64];
        const int mn = (mt0 + mtn) * 16 + lm;
        f32x2 nmA = {1.f, vb[mn]}, nmB = {vb[MM + mn], vb[2 * MM + mn]};

#pragma unroll
        for (int r = 0; r < RQ; ++r) {
            facc4 d = {0.f, 0.f, 0.f, 0.f};
            d = __builtin_amdgcn_mfma_f32_16x16x32_f16(qf[r][0], k0, d, 0, 0, 0);
            d = __builtin_amdgcn_mfma_f32_16x16x32_f16(qf[r][1], k1, d, 0, 0, 0);
#pragma unroll
            for (int e = 0; e < 4; ++e) {
                float p = __builtin_amdgcn_exp2f(d[e]);   // raw v_exp_f32
                f32x2 p2 = {p, p};
                accA[r][e] = p2 * mA + accA[r][e];        // v_pk_fma_f32
                accB[r][e] = p2 * mB + accB[r][e];        // v_pk_fma_f32
            }
        }
        k0 = nk0; k1 = nk1; mA = nmA; mB = nmB;
    }

    // ---- reduce across the 16 key-lanes of each quarter-wave ----
    float* pout = PART + (((size_t)(b * MSPLIT + ms) * NN) + n0) * 4;
#pragma unroll
    for (int r = 0; r < RQ; ++r) {
#pragma unroll
        for (int e = 0; e < 4; ++e) {
            float L = accA[r][e].x, a0 = accA[r][e].y;
            float a1 = accB[r][e].x, a2 = accB[r][e].y;
#pragma unroll
            for (int off = 1; off < 16; off <<= 1) {
                L  += __shfl_xor(L,  off);
                a0 += __shfl_xor(a0, off);
                a1 += __shfl_xor(a1, off);
                a2 += __shfl_xor(a2, off);
            }
            if (lm == 0) {
                int nl = 16 * r + 4 * lq + e;
                facc4 o = {L, a0, a1, a2};
                *(facc4*)(pout + (size_t)nl * 4) = o;
            }
        }
    }
}

// ---------------------------------------------------------------------------
// Merged epilogue: 32 blocks (one per batch) x 256 threads.
// Each thread covers 8 n values; merge msplit partials, normalize, 15 stats;
// block-reduce (shfl + LDS); thread 0 does the f64 Kabsch SVD and writes.
// out: R flat [B,3,3] at [0..287], t [B,3] at [288..383]
// ---------------------------------------------------------------------------
__global__ __launch_bounds__(256) void reduce_svd(
    const float* __restrict__ PART,
    const float* __restrict__ ACP,  // action_points [B,3,N]
    float* __restrict__ out)
{
    const int b = blockIdx.x;
    const int t = threadIdx.x;
    const int lane = t & 63;
    const int w    = t >> 6;

    const float* ab = ACP + (size_t)b * 3 * NN;

    float vals[15] = {};
    for (int n = t; n < NN; n += 256) {
        facc4 s = {0.f, 0.f, 0.f, 0.f};
#pragma unroll
        for (int ms = 0; ms < MSPLIT; ++ms)
            s += *(const facc4*)(PART + (((size_t)(b * MSPLIT + ms) * NN) + n) * 4);
        float inv = 1.f / s[0];
        float c0 = s[1] * inv, c1 = s[2] * inv, c2 = s[3] * inv;
        float A0 = ab[n], A1 = ab[NN + n], A2 = ab[2 * NN + n];
        vals[0] += A0; vals[1] += A1; vals[2] += A2;
        vals[3] += c0; vals[4] += c1; vals[5] += c2;
        vals[6]  = fmaf(A0, c0, vals[6]);  vals[7]  = fmaf(A0, c1, vals[7]);  vals[8]  = fmaf(A0, c2, vals[8]);
        vals[9]  = fmaf(A1, c0, vals[9]);  vals[10] = fmaf(A1, c1, vals[10]); vals[11] = fmaf(A1, c2, vals[11]);
        vals[12] = fmaf(A2, c0, vals[12]); vals[13] = fmaf(A2, c1, vals[13]); vals[14] = fmaf(A2, c2, vals[14]);
    }

#pragma unroll
    for (int k = 0; k < 15; ++k) {
        float v = vals[k];
        for (int off = 32; off > 0; off >>= 1) v += __shfl_xor(v, off);
        vals[k] = v;
    }

    __shared__ float rbuf[4][15];
    if (lane == 0) {
#pragma unroll
        for (int k = 0; k < 15; ++k) rbuf[w][k] = vals[k];
    }
    __syncthreads();

    if (t == 0) {
        double tot[15];
#pragma unroll
        for (int k = 0; k < 15; ++k)
            tot[k] = (double)rbuf[0][k] + rbuf[1][k] + rbuf[2][k] + rbuf[3][k];

        double am[3], cm[3];
        for (int i = 0; i < 3; ++i) {
            am[i] = tot[i] / (double)NN;
            cm[i] = tot[3 + i] / (double)NN;
        }
        double H[3][3];
        for (int i = 0; i < 3; ++i)
            for (int j = 0; j < 3; ++j)
                H[i][j] = tot[6 + 3 * i + j] - (double)NN * am[i] * cm[j];

        double K[3][3];
        for (int i = 0; i < 3; ++i)
            for (int j = 0; j < 3; ++j)
                K[i][j] = H[0][i] * H[0][j] + H[1][i] * H[1][j] + H[2][i] * H[2][j];
        double V[3][3] = {{1, 0, 0}, {0, 1, 0}, {0, 0, 1}};
        for (int sweep = 0; sweep < 12; ++sweep) {
            for (int pi = 0; pi < 3; ++pi) {
                int p = (pi == 2) ? 1 : 0;
                int qq = (pi == 0) ? 1 : 2;
                double apq = K[p][qq];
                if (fabs(apq) < 1e-300) continue;
                double app = K[p][p], aqq2 = K[qq][qq];
                double tau = (aqq2 - app) / (2.0 * apq);
                double tt = ((tau >= 0.0) ? 1.0 : -1.0) / (fabs(tau) + sqrt(1.0 + tau * tau));
                double c = 1.0 / sqrt(1.0 + tt * tt);
                double s = tt * c;
                for (int k = 0; k < 3; ++k) {
                    double kp = K[k][p], kq = K[k][qq];
                    K[k][p] = c * kp - s * kq; K[k][qq] = s * kp + c * kq;
                }
                for (int k = 0; k < 3; ++k) {
                    double kp = K[p][k], kq = K[qq][k];
                    K[p][k] = c * kp - s * kq; K[qq][k] = s * kp + c * kq;
                }
                for (int k = 0; k < 3; ++k) {
                    double vp = V[k][p], vq = V[k][qq];
                    V[k][p] = c * vp - s * vq; V[k][qq] = s * vp + c * vq;
                }
            }
        }
        double lam[3] = {K[0][0], K[1][1], K[2][2]};
        for (int i = 0; i < 2; ++i)
            for (int j = i + 1; j < 3; ++j)
                if (lam[j] > lam[i]) {
                    double tmp = lam[i]; lam[i] = lam[j]; lam[j] = tmp;
                    for (int k = 0; k < 3; ++k) {
                        double tv = V[k][i]; V[k][i] = V[k][j]; V[k][j] = tv;
                    }
                }
        double U[3][3], sig[3];
        for (int k = 0; k < 3; ++k) {
            double u0 = H[0][0] * V[0][k] + H[0][1] * V[1][k] + H[0][2] * V[2][k];
            double u1 = H[1][0] * V[0][k] + H[1][1] * V[1][k] + H[1][2] * V[2][k];
            double u2 = H[2][0] * V[0][k] + H[2][1] * V[1][k] + H[2][2] * V[2][k];
            double nrm = sqrt(u0 * u0 + u1 * u1 + u2 * u2);
            sig[k] = nrm;
            double inv = (nrm > 1e-30) ? 1.0 / nrm : 0.0;
            U[0][k] = u0 * inv; U[1][k] = u1 * inv; U[2][k] = u2 * inv;
        }
        if (sig[2] <= 1e-10 * fmax(sig[0], 1e-300)) {
            U[0][2] = U[1][0] * U[2][1] - U[2][0] * U[1][1];
            U[1][2] = U[2][0] * U[0][1] - U[0][0] * U[2][1];
            U[2][2] = U[0][0] * U[1][1] - U[1][0] * U[0][1];
        }
        {
            double d01 = U[0][1] * U[0][0] + U[1][1] * U[1][0] + U[2][1] * U[2][0];
            for (int i = 0; i < 3; ++i) U[i][1] -= d01 * U[i][0];
            double n1 = sqrt(U[0][1] * U[0][1] + U[1][1] * U[1][1] + U[2][1] * U[2][1]);
            if (n1 > 1e-30) for (int i = 0; i < 3; ++i) U[i][1] /= n1;
            double d02 = U[0][2] * U[0][0] + U[1][2] * U[1][0] + U[2][2] * U[2][0];
            double d12 = U[0][2] * U[0][1] + U[1][2] * U[1][1] + U[2][2] * U[2][1];
            for (int i = 0; i < 3; ++i) U[i][2] -= d02 * U[i][0] + d12 * U[i][1];
            double n2 = sqrt(U[0][2] * U[0][2] + U[1][2] * U[1][2] + U[2][2] * U[2][2]);
            if (n2 > 1e-30) for (int i = 0; i < 3; ++i) U[i][2] /= n2;
        }

        double detH =
            H[0][0] * (H[1][1] * H[2][2] - H[1][2] * H[2][1]) -
            H[0][1] * (H[1][0] * H[2][2] - H[1][2] * H[2][0]) +
            H[0][2] * (H[1][0] * H[2][1] - H[1][1] * H[2][0]);
        double s3 = (detH < 0.0) ? -1.0 : 1.0;

        double R[3][3];
        for (int i = 0; i < 3; ++i)
            for (int j = 0; j < 3; ++j)
                R[i][j] = V[i][0] * U[j][0] + V[i][1] * U[j][1] + s3 * V[i][2] * U[j][2];

        double tv[3];
        for (int i = 0; i < 3; ++i)
            tv[i] = cm[i] - (R[i][0] * am[0] + R[i][1] * am[1] + R[i][2] * am[2]);

        float* Rout = out + (size_t)b * 9;
        for (int i = 0; i < 3; ++i)
            for (int j = 0; j < 3; ++j)
                Rout[3 * i + j] = (float)R[i][j];
        float* Tout = out + 288 + (size_t)b * 3;
        for (int i = 0; i < 3; ++i) Tout[i] = (float)tv[i];
    }
}

extern "C" void kernel_launch(void* const* d_in, const int* in_sizes, int n_in,
                              void* d_out, int out_size, void* d_ws, size_t ws_size,
                              hipStream_t stream) {
    (void)in_sizes; (void)n_in; (void)out_size; (void)ws_size;
    const float* AE  = (const float*)d_in[0];  // action_embedding [B,64,N]
    const float* KE  = (const float*)d_in[1];  // anchor_embedding [B,64,M]
    const float* ACP = (const float*)d_in[2];  // action_points    [B,3,N]
    const float* ANP = (const float*)d_in[3];  // anchor_points    [B,3,M]
    float* out = (float*)d_out;

    hfrag8* KH   = (hfrag8*)d_ws;                          // 8 MB fp16 frags
    float*  PART = (float*)((char*)d_ws + (8u << 20));     // 4 MB partials

    prep_k<<<dim3(MM / 64, BB), 256, 0, stream>>>(KE, KH);
    attn_main<<<dim3(MSPLIT, NN / (32 * 4), BB), 256, 0, stream>>>(AE, ANP, KH, PART);
    reduce_svd<<<BB, 256, 0, stream>>>(PART, ACP, out);
}

// Round 10
// 139.888 us; speedup vs baseline: 4.3299x; 4.3299x over previous
//
#include <hip/hip_runtime.h>
#include <math.h>

#define BB 32
#define DKK 64
#define NN 2048
#define MM 2048
#define MSPLIT 4
#define RQ 2            // 16-row query tiles per wave (32 queries/wave)

typedef __attribute__((ext_vector_type(8))) _Float16 hfrag8;  // 8 fp16 (4 VGPRs)
typedef __attribute__((ext_vector_type(4))) float facc4;      // 4 f32

// ---------------------------------------------------------------------------
// Pre-pass: KE [B][64][M] f32 -> KH fragment-ready fp16
// frag layout per (b, mt16, dchunk): 64 lanes x 8 el;
//   element (lane,j) = K[d = 32*dchunk + 8*(lane>>4) + j][m = 16*mt16 + (lane&15)]
// ---------------------------------------------------------------------------
__global__ __launch_bounds__(256) void prep_k(const float* __restrict__ KE,
                                              hfrag8* __restrict__ KH)
{
    const int b = blockIdx.y, mb = blockIdx.x;
    const int t = threadIdx.x;
    const int seg = t >> 6, lane = t & 63;
    __shared__ float T[64][65];

    const float* src = KE + (size_t)b * 64 * MM + mb * 64;
#pragma unroll
    for (int i = 0; i < 16; ++i) {
        int d = i * 4 + seg;
        T[d][lane] = src[(size_t)d * MM + lane];
    }
    __syncthreads();

    const int lq = lane >> 4, lm = lane & 15;
#pragma unroll
    for (int p = 0; p < 2; ++p) {
        hfrag8 f;
#pragma unroll
        for (int j = 0; j < 8; ++j)
            f[j] = (_Float16)T[32 * p + 8 * lq + j][16 * seg + lm];
        KH[((size_t)(b * 128 + mb * 4 + seg) * 2 + p) * 64 + lane] = f;
    }
}

// ---------------------------------------------------------------------------
// Main flash kernel: 4 independent waves/block (no barriers, no LDS).
// Wave owns 32 queries; M split 4 ways. Single-pass fp16 MFMA.
// Q pre-scaled by log2(e)/8 so p = v_exp_f32(score) directly (raw builtin,
// no OCML guard code). Scalar f32 accumulator arrays (promote to VGPRs;
// ext_vector arrays would spill to scratch - r9 lesson).
// PART[b][ms][n][4] = {l, a0, a1, a2}
// ---------------------------------------------------------------------------
__global__ __launch_bounds__(256, 4) void attn_main(
    const float* __restrict__ AE,   // action_embedding [B,64,N]
    const float* __restrict__ ANP,  // anchor_points    [B,3,M]
    const hfrag8* __restrict__ KH,
    float* __restrict__ PART)
{
    const int t = threadIdx.x;
    const int w = t >> 6, l = t & 63;
    const int ms = blockIdx.x, b = blockIdx.z;
    const int nw = blockIdx.y * 4 + w;   // 0..63
    const int n0 = nw * 32;
    const int lq = l >> 4, lm = l & 15;

    // ---- gather Q fragments once, prescaled, fp16 ----
    const float SC = 0.125f * 1.44269504088896340736f;
    hfrag8 qf[RQ][2];
    const float* qbase = AE + (size_t)b * 64 * NN + n0 + lm;
#pragma unroll
    for (int r = 0; r < RQ; ++r) {
#pragma unroll
        for (int c = 0; c < 2; ++c) {
            hfrag8 f;
#pragma unroll
            for (int j = 0; j < 8; ++j) {
                int d = 32 * c + 8 * lq + j;
                f[j] = (_Float16)(qbase[(size_t)d * NN + 16 * r] * SC);
            }
            qf[r][c] = f;
        }
    }

    float accL[RQ][4] = {}, acc0[RQ][4] = {}, acc1[RQ][4] = {}, acc2[RQ][4] = {};

    const hfrag8* kb = KH + (size_t)b * 128 * 2 * 64;
    const float* vb = ANP + (size_t)b * 3 * MM;
    const int mt0 = ms * 32;   // 32 16-key tiles per (b,ms)

    // prologue: tile 0 into registers
    size_t kidx = ((size_t)mt0 * 2) * 64 + l;
    hfrag8 k0 = kb[kidx], k1 = kb[kidx + 64];
    int m = mt0 * 16 + lm;
    float v0 = vb[m], v1 = vb[MM + m], v2 = vb[2 * MM + m];

    for (int mt = 0; mt < 32; ++mt) {
        const int mtn = (mt + 1) & 31;   // wrap: last prefetch re-reads tile 0 (L2 hit)
        size_t kidx2 = ((size_t)(mt0 + mtn) * 2) * 64 + l;
        hfrag8 nk0 = kb[kidx2], nk1 = kb[kidx2 + 64];
        const int mn = (mt0 + mtn) * 16 + lm;
        float nv0 = vb[mn], nv1 = vb[MM + mn], nv2 = vb[2 * MM + mn];

#pragma unroll
        for (int r = 0; r < RQ; ++r) {
            facc4 d = {0.f, 0.f, 0.f, 0.f};
            d = __builtin_amdgcn_mfma_f32_16x16x32_f16(qf[r][0], k0, d, 0, 0, 0);
            d = __builtin_amdgcn_mfma_f32_16x16x32_f16(qf[r][1], k1, d, 0, 0, 0);
#pragma unroll
            for (int e = 0; e < 4; ++e) {
                float p = __builtin_amdgcn_exp2f(d[e]);   // raw v_exp_f32
                accL[r][e] += p;
                acc0[r][e] = fmaf(p, v0, acc0[r][e]);
                acc1[r][e] = fmaf(p, v1, acc1[r][e]);
                acc2[r][e] = fmaf(p, v2, acc2[r][e]);
            }
        }
        k0 = nk0; k1 = nk1; v0 = nv0; v1 = nv1; v2 = nv2;
    }

    // ---- reduce across the 16 key-lanes of each quarter-wave ----
    float* pout = PART + (((size_t)(b * MSPLIT + ms) * NN) + n0) * 4;
#pragma unroll
    for (int r = 0; r < RQ; ++r) {
#pragma unroll
        for (int e = 0; e < 4; ++e) {
            float L = accL[r][e], a0 = acc0[r][e], a1 = acc1[r][e], a2 = acc2[r][e];
#pragma unroll
            for (int off = 1; off < 16; off <<= 1) {
                L  += __shfl_xor(L,  off);
                a0 += __shfl_xor(a0, off);
                a1 += __shfl_xor(a1, off);
                a2 += __shfl_xor(a2, off);
            }
            if (lm == 0) {
                int nl = 16 * r + 4 * lq + e;
                facc4 o = {L, a0, a1, a2};
                *(facc4*)(pout + (size_t)nl * 4) = o;
            }
        }
    }
}

// ---------------------------------------------------------------------------
// Merged epilogue: 32 blocks (one per batch) x 256 threads.
// Each thread covers 8 n values; merge msplit partials, normalize, 15 stats;
// block-reduce (shfl + LDS); thread 0 does the f64 Kabsch SVD and writes.
// out: R flat [B,3,3] at [0..287], t [B,3] at [288..383]
// ---------------------------------------------------------------------------
__global__ __launch_bounds__(256) void reduce_svd(
    const float* __restrict__ PART,
    const float* __restrict__ ACP,  // action_points [B,3,N]
    float* __restrict__ out)
{
    const int b = blockIdx.x;
    const int t = threadIdx.x;
    const int lane = t & 63;
    const int w    = t >> 6;

    const float* ab = ACP + (size_t)b * 3 * NN;

    float vals[15] = {};
    for (int n = t; n < NN; n += 256) {
        facc4 s = {0.f, 0.f, 0.f, 0.f};
#pragma unroll
        for (int ms = 0; ms < MSPLIT; ++ms)
            s += *(const facc4*)(PART + (((size_t)(b * MSPLIT + ms) * NN) + n) * 4);
        float inv = 1.f / s[0];
        float c0 = s[1] * inv, c1 = s[2] * inv, c2 = s[3] * inv;
        float A0 = ab[n], A1 = ab[NN + n], A2 = ab[2 * NN + n];
        vals[0] += A0; vals[1] += A1; vals[2] += A2;
        vals[3] += c0; vals[4] += c1; vals[5] += c2;
        vals[6]  = fmaf(A0, c0, vals[6]);  vals[7]  = fmaf(A0, c1, vals[7]);  vals[8]  = fmaf(A0, c2, vals[8]);
        vals[9]  = fmaf(A1, c0, vals[9]);  vals[10] = fmaf(A1, c1, vals[10]); vals[11] = fmaf(A1, c2, vals[11]);
        vals[12] = fmaf(A2, c0, vals[12]); vals[13] = fmaf(A2, c1, vals[13]); vals[14] = fmaf(A2, c2, vals[14]);
    }

#pragma unroll
    for (int k = 0; k < 15; ++k) {
        float v = vals[k];
        for (int off = 32; off > 0; off >>= 1) v += __shfl_xor(v, off);
        vals[k] = v;
    }

    __shared__ float rbuf[4][15];
    if (lane == 0) {
#pragma unroll
        for (int k = 0; k < 15; ++k) rbuf[w][k] = vals[k];
    }
    __syncthreads();

    if (t == 0) {
        double tot[15];
#pragma unroll
        for (int k = 0; k < 15; ++k)
            tot[k] = (double)rbuf[0][k] + rbuf[1][k] + rbuf[2][k] + rbuf[3][k];

        double am[3], cm[3];
        for (int i = 0; i < 3; ++i) {
            am[i] = tot[i] / (double)NN;
            cm[i] = tot[3 + i] / (double)NN;
        }
        double H[3][3];
        for (int i = 0; i < 3; ++i)
            for (int j = 0; j < 3; ++j)
                H[i][j] = tot[6 + 3 * i + j] - (double)NN * am[i] * cm[j];

        double K[3][3];
        for (int i = 0; i < 3; ++i)
            for (int j = 0; j < 3; ++j)
                K[i][j] = H[0][i] * H[0][j] + H[1][i] * H[1][j] + H[2][i] * H[2][j];
        double V[3][3] = {{1, 0, 0}, {0, 1, 0}, {0, 0, 1}};
        for (int sweep = 0; sweep < 12; ++sweep) {
            for (int pi = 0; pi < 3; ++pi) {
                int p = (pi == 2) ? 1 : 0;
                int qq = (pi == 0) ? 1 : 2;
                double apq = K[p][qq];
                if (fabs(apq) < 1e-300) continue;
                double app = K[p][p], aqq2 = K[qq][qq];
                double tau = (aqq2 - app) / (2.0 * apq);
                double tt = ((tau >= 0.0) ? 1.0 : -1.0) / (fabs(tau) + sqrt(1.0 + tau * tau));
                double c = 1.0 / sqrt(1.0 + tt * tt);
                double s = tt * c;
                for (int k = 0; k < 3; ++k) {
                    double kp = K[k][p], kq = K[k][qq];
                    K[k][p] = c * kp - s * kq; K[k][qq] = s * kp + c * kq;
                }
                for (int k = 0; k < 3; ++k) {
                    double kp = K[p][k], kq = K[qq][k];
                    K[p][k] = c * kp - s * kq; K[qq][k] = s * kp + c * kq;
                }
                for (int k = 0; k < 3; ++k) {
                    double vp = V[k][p], vq = V[k][qq];
                    V[k][p] = c * vp - s * vq; V[k][qq] = s * vp + c * vq;
                }
            }
        }
        double lam[3] = {K[0][0], K[1][1], K[2][2]};
        for (int i = 0; i < 2; ++i)
            for (int j = i + 1; j < 3; ++j)
                if (lam[j] > lam[i]) {
                    double tmp = lam[i]; lam[i] = lam[j]; lam[j] = tmp;
                    for (int k = 0; k < 3; ++k) {
                        double tv = V[k][i]; V[k][i] = V[k][j]; V[k][j] = tv;
                    }
                }
        double U[3][3], sig[3];
        for (int k = 0; k < 3; ++k) {
            double u0 = H[0][0] * V[0][k] + H[0][1] * V[1][k] + H[0][2] * V[2][k];
            double u1 = H[1][0] * V[0][k] + H[1][1] * V[1][k] + H[1][2] * V[2][k];
            double u2 = H[2][0] * V[0][k] + H[2][1] * V[1][k] + H[2][2] * V[2][k];
            double nrm = sqrt(u0 * u0 + u1 * u1 + u2 * u2);
            sig[k] = nrm;
            double inv = (nrm > 1e-30) ? 1.0 / nrm : 0.0;
            U[0][k] = u0 * inv; U[1][k] = u1 * inv; U[2][k] = u2 * inv;
        }
        if (sig[2] <= 1e-10 * fmax(sig[0], 1e-300)) {
            U[0][2] = U[1][0] * U[2][1] - U[2][0] * U[1][1];
            U[1][2] = U[2][0] * U[0][1] - U[0][0] * U[2][1];
            U[2][2] = U[0][0] * U[1][1] - U[1][0] * U[0][1];
        }
        {
            double d01 = U[0][1] * U[0][0] + U[1][1] * U[1][0] + U[2][1] * U[2][0];
            for (int i = 0; i < 3; ++i) U[i][1] -= d01 * U[i][0];
            double n1 = sqrt(U[0][1] * U[0][1] + U[1][1] * U[1][1] + U[2][1] * U[2][1]);
            if (n1 > 1e-30) for (int i = 0; i < 3; ++i) U[i][1] /= n1;
            double d02 = U[0][2] * U[0][0] + U[1][2] * U[1][0] + U[2][2] * U[2][0];
            double d12 = U[0][2] * U[0][1] + U[1][2] * U[1][1] + U[2][2] * U[2][1];
            for (int i = 0; i < 3; ++i) U[i][2] -= d02 * U[i][0] + d12 * U[i][1];
            double n2 = sqrt(U[0][2] * U[0][2] + U[1][2] * U[1][2] + U[2][2] * U[2][2]);
            if (n2 > 1e-30) for (int i = 0; i < 3; ++i) U[i][2] /= n2;
        }

        double detH =
            H[0][0] * (H[1][1] * H[2][2] - H[1][2] * H[2][1]) -
            H[0][1] * (H[1][0] * H[2][2] - H[1][2] * H[2][0]) +
            H[0][2] * (H[1][0] * H[2][1] - H[1][1] * H[2][0]);
        double s3 = (detH < 0.0) ? -1.0 : 1.0;

        double R[3][3];
        for (int i = 0; i < 3; ++i)
            for (int j = 0; j < 3; ++j)
                R[i][j] = V[i][0] * U[j][0] + V[i][1] * U[j][1] + s3 * V[i][2] * U[j][2];

        double tv[3];
        for (int i = 0; i < 3; ++i)
            tv[i] = cm[i] - (R[i][0] * am[0] + R[i][1] * am[1] + R[i][2] * am[2]);

        float* Rout = out + (size_t)b * 9;
        for (int i = 0; i < 3; ++i)
            for (int j = 0; j < 3; ++j)
                Rout[3 * i + j] = (float)R[i][j];
        float* Tout = out + 288 + (size_t)b * 3;
        for (int i = 0; i < 3; ++i) Tout[i] = (float)tv[i];
    }
}

extern "C" void kernel_launch(void* const* d_in, const int* in_sizes, int n_in,
                              void* d_out, int out_size, void* d_ws, size_t ws_size,
                              hipStream_t stream) {
    (void)in_sizes; (void)n_in; (void)out_size; (void)ws_size;
    const float* AE  = (const float*)d_in[0];  // action_embedding [B,64,N]
    const float* KE  = (const float*)d_in[1];  // anchor_embedding [B,64,M]
    const float* ACP = (const float*)d_in[2];  // action_points    [B,3,N]
    const float* ANP = (const float*)d_in[3];  // anchor_points    [B,3,M]
    float* out = (float*)d_out;

    hfrag8* KH   = (hfrag8*)d_ws;                          // 8 MB fp16 frags
    float*  PART = (float*)((char*)d_ws + (8u << 20));     // 4 MB partials

    prep_k<<<dim3(MM / 64, BB), 256, 0, stream>>>(KE, KH);
    attn_main<<<dim3(MSPLIT, NN / (32 * 4), BB), 256, 0, stream>>>(AE, ANP, KH, PART);
    reduce_svd<<<BB, 256, 0, stream>>>(PART, ACP, out);
}

// Round 11
// 137.840 us; speedup vs baseline: 4.3942x; 1.0149x over previous
//
#include <hip/hip_runtime.h>
#include <math.h>

#define BB 32
#define DKK 64
#define NN 2048
#define MM 2048
#define MSPLIT 4
#define RQ 2            // 16-row query tiles per wave (32 queries/wave)

typedef __attribute__((ext_vector_type(8))) _Float16 hfrag8;  // 8 fp16 (4 VGPRs)
typedef __attribute__((ext_vector_type(4))) float facc4;      // 4 f32

// ---------------------------------------------------------------------------
// Pre-pass: KE [B][64][M] f32 -> KH fragment-ready fp16, and ANP -> VP float4
// frag layout per (b, mt16, dchunk): 64 lanes x 8 el;
//   element (lane,j) = K[d = 32*dchunk + 8*(lane>>4) + j][m = 16*mt16 + (lane&15)]
// VP[b][m] = {v0, v1, v2, 1.0}
// ---------------------------------------------------------------------------
__global__ __launch_bounds__(256) void prep_k(const float* __restrict__ KE,
                                              const float* __restrict__ ANP,
                                              hfrag8* __restrict__ KH,
                                              facc4* __restrict__ VP)
{
    const int b = blockIdx.y, mb = blockIdx.x;
    const int t = threadIdx.x;
    const int seg = t >> 6, lane = t & 63;
    __shared__ float T[64][65];

    const float* src = KE + (size_t)b * 64 * MM + mb * 64;
#pragma unroll
    for (int i = 0; i < 16; ++i) {
        int d = i * 4 + seg;
        T[d][lane] = src[(size_t)d * MM + lane];
    }

    // V packing (independent of LDS): threads 0..63 cover this 64-m chunk
    if (t < 64) {
        const float* vb = ANP + (size_t)b * 3 * MM;
        int m = mb * 64 + t;
        facc4 o = {vb[m], vb[MM + m], vb[2 * MM + m], 1.0f};
        VP[(size_t)b * MM + m] = o;
    }

    __syncthreads();

    const int lq = lane >> 4, lm = lane & 15;
#pragma unroll
    for (int p = 0; p < 2; ++p) {
        hfrag8 f;
#pragma unroll
        for (int j = 0; j < 8; ++j)
            f[j] = (_Float16)T[32 * p + 8 * lq + j][16 * seg + lm];
        KH[((size_t)(b * 128 + mb * 4 + seg) * 2 + p) * 64 + lane] = f;
    }
}

// ---------------------------------------------------------------------------
// Main flash kernel: 4 independent waves/block (no barriers, no LDS).
// Wave owns 32 queries; M split 4 ways. Single-pass fp16 MFMA.
// Q pre-scaled by log2(e)/8 so p = v_exp_f32(score) directly.
// V as one coalesced float4 load per 16-key tile.
// PART[b][ms][n][4] = {l, a0, a1, a2}
// ---------------------------------------------------------------------------
__global__ __launch_bounds__(256, 4) void attn_main(
    const float* __restrict__ AE,   // action_embedding [B,64,N]
    const facc4* __restrict__ VP,   // packed anchor points [B][M]
    const hfrag8* __restrict__ KH,
    float* __restrict__ PART)
{
    const int t = threadIdx.x;
    const int w = t >> 6, l = t & 63;
    const int ms = blockIdx.x, b = blockIdx.z;
    const int nw = blockIdx.y * 4 + w;   // 0..63
    const int n0 = nw * 32;
    const int lq = l >> 4, lm = l & 15;

    // ---- gather Q fragments once, prescaled, fp16 ----
    const float SC = 0.125f * 1.44269504088896340736f;
    hfrag8 qf[RQ][2];
    const float* qbase = AE + (size_t)b * 64 * NN + n0 + lm;
#pragma unroll
    for (int r = 0; r < RQ; ++r) {
#pragma unroll
        for (int c = 0; c < 2; ++c) {
            hfrag8 f;
#pragma unroll
            for (int j = 0; j < 8; ++j) {
                int d = 32 * c + 8 * lq + j;
                f[j] = (_Float16)(qbase[(size_t)d * NN + 16 * r] * SC);
            }
            qf[r][c] = f;
        }
    }

    float accL[RQ][4] = {}, acc0[RQ][4] = {}, acc1[RQ][4] = {}, acc2[RQ][4] = {};

    const hfrag8* kb = KH + (size_t)b * 128 * 2 * 64;
    const facc4* vp = VP + (size_t)b * MM;
    const int mt0 = ms * 32;   // 32 16-key tiles per (b,ms)

    // prologue: tile 0 into registers
    size_t kidx = ((size_t)mt0 * 2) * 64 + l;
    hfrag8 k0 = kb[kidx], k1 = kb[kidx + 64];
    facc4 vv = vp[mt0 * 16 + lm];

#pragma unroll 2
    for (int mt = 0; mt < 32; ++mt) {
        const int mtn = (mt + 1) & 31;   // wrap: last prefetch re-reads tile 0 (L2 hit)
        size_t kidx2 = ((size_t)(mt0 + mtn) * 2) * 64 + l;
        hfrag8 nk0 = kb[kidx2], nk1 = kb[kidx2 + 64];
        facc4 nvv = vp[(mt0 + mtn) * 16 + lm];

        float v0 = vv.x, v1 = vv.y, v2 = vv.z;
#pragma unroll
        for (int r = 0; r < RQ; ++r) {
            facc4 d = {0.f, 0.f, 0.f, 0.f};
            d = __builtin_amdgcn_mfma_f32_16x16x32_f16(qf[r][0], k0, d, 0, 0, 0);
            d = __builtin_amdgcn_mfma_f32_16x16x32_f16(qf[r][1], k1, d, 0, 0, 0);
#pragma unroll
            for (int e = 0; e < 4; ++e) {
                float p = __builtin_amdgcn_exp2f(d[e]);   // raw v_exp_f32
                accL[r][e] += p;
                acc0[r][e] = fmaf(p, v0, acc0[r][e]);
                acc1[r][e] = fmaf(p, v1, acc1[r][e]);
                acc2[r][e] = fmaf(p, v2, acc2[r][e]);
            }
        }
        k0 = nk0; k1 = nk1; vv = nvv;
    }

    // ---- reduce across the 16 key-lanes of each quarter-wave ----
    float* pout = PART + (((size_t)(b * MSPLIT + ms) * NN) + n0) * 4;
#pragma unroll
    for (int r = 0; r < RQ; ++r) {
#pragma unroll
        for (int e = 0; e < 4; ++e) {
            float L = accL[r][e], a0 = acc0[r][e], a1 = acc1[r][e], a2 = acc2[r][e];
#pragma unroll
            for (int off = 1; off < 16; off <<= 1) {
                L  += __shfl_xor(L,  off);
                a0 += __shfl_xor(a0, off);
                a1 += __shfl_xor(a1, off);
                a2 += __shfl_xor(a2, off);
            }
            if (lm == 0) {
                int nl = 16 * r + 4 * lq + e;
                facc4 o = {L, a0, a1, a2};
                *(facc4*)(pout + (size_t)nl * 4) = o;
            }
        }
    }
}

// ---------------------------------------------------------------------------
// Stage 1 of epilogue: 256 blocks = 32 batches x 8 n-chunks.
// Merge msplit partials, normalize, 15 stats, block-reduce, PART2[bc][16].
// ---------------------------------------------------------------------------
__global__ __launch_bounds__(256) void reduce_part(
    const float* __restrict__ PART,
    const float* __restrict__ ACP,  // action_points [B,3,N]
    float* __restrict__ PART2)
{
    const int bc = blockIdx.x;           // 0..255
    const int b = bc >> 3, ch = bc & 7;
    const int t = threadIdx.x;
    const int lane = t & 63;
    const int w    = t >> 6;
    const int n = ch * 256 + t;

    const float* ab = ACP + (size_t)b * 3 * NN;

    facc4 s = {0.f, 0.f, 0.f, 0.f};
#pragma unroll
    for (int ms = 0; ms < MSPLIT; ++ms)
        s += *(const facc4*)(PART + (((size_t)(b * MSPLIT + ms) * NN) + n) * 4);
    float inv = 1.f / s[0];
    float c0 = s[1] * inv, c1 = s[2] * inv, c2 = s[3] * inv;
    float A0 = ab[n], A1 = ab[NN + n], A2 = ab[2 * NN + n];

    float vals[15];
    vals[0] = A0; vals[1] = A1; vals[2] = A2;
    vals[3] = c0; vals[4] = c1; vals[5] = c2;
    vals[6]  = A0 * c0; vals[7]  = A0 * c1; vals[8]  = A0 * c2;
    vals[9]  = A1 * c0; vals[10] = A1 * c1; vals[11] = A1 * c2;
    vals[12] = A2 * c0; vals[13] = A2 * c1; vals[14] = A2 * c2;

#pragma unroll
    for (int k = 0; k < 15; ++k) {
        float v = vals[k];
        for (int off = 32; off > 0; off >>= 1) v += __shfl_xor(v, off);
        vals[k] = v;
    }

    __shared__ float rbuf[4][15];
    if (lane == 0) {
#pragma unroll
        for (int k = 0; k < 15; ++k) rbuf[w][k] = vals[k];
    }
    __syncthreads();
    if (t < 15)
        PART2[(size_t)bc * 16 + t] =
            rbuf[0][t] + rbuf[1][t] + rbuf[2][t] + rbuf[3][t];
}

// ---------------------------------------------------------------------------
// Stage 2: one wave; lane b (<32) does batch b's full f64 Kabsch SIMT.
// out: R flat [B,3,3] at [0..287], t [B,3] at [288..383]
// ---------------------------------------------------------------------------
__global__ __launch_bounds__(64) void svd_final(
    const float* __restrict__ PART2,
    float* __restrict__ out)
{
    const int b = threadIdx.x;
    if (b >= 32) return;

    double tot[15];
#pragma unroll
    for (int k = 0; k < 15; ++k) {
        double a = 0.0;
#pragma unroll
        for (int ch = 0; ch < 8; ++ch)
            a += (double)PART2[(size_t)(b * 8 + ch) * 16 + k];
        tot[k] = a;
    }

    double am[3], cm[3];
    for (int i = 0; i < 3; ++i) {
        am[i] = tot[i] / (double)NN;
        cm[i] = tot[3 + i] / (double)NN;
    }
    double H[3][3];
    for (int i = 0; i < 3; ++i)
        for (int j = 0; j < 3; ++j)
            H[i][j] = tot[6 + 3 * i + j] - (double)NN * am[i] * cm[j];

    // K = H^T H, Jacobi eigen -> V (branchless rotations)
    double K[3][3];
    for (int i = 0; i < 3; ++i)
        for (int j = 0; j < 3; ++j)
            K[i][j] = H[0][i] * H[0][j] + H[1][i] * H[1][j] + H[2][i] * H[2][j];
    double V[3][3] = {{1, 0, 0}, {0, 1, 0}, {0, 0, 1}};
    for (int sweep = 0; sweep < 12; ++sweep) {
        for (int pi = 0; pi < 3; ++pi) {
            int p = (pi == 2) ? 1 : 0;
            int qq = (pi == 0) ? 1 : 2;
            double apq = K[p][qq];
            double apq_s = (fabs(apq) < 1e-300) ? 1e-300 : apq;   // -> identity rotation
            double app = K[p][p], aqq2 = K[qq][qq];
            double tau = (aqq2 - app) / (2.0 * apq_s);
            double tt = ((tau >= 0.0) ? 1.0 : -1.0) / (fabs(tau) + sqrt(1.0 + tau * tau));
            tt = (fabs(apq) < 1e-300) ? 0.0 : tt;
            double c = 1.0 / sqrt(1.0 + tt * tt);
            double s = tt * c;
            for (int k = 0; k < 3; ++k) {
                double kp = K[k][p], kq = K[k][qq];
                K[k][p] = c * kp - s * kq; K[k][qq] = s * kp + c * kq;
            }
            for (int k = 0; k < 3; ++k) {
                double kp = K[p][k], kq = K[qq][k];
                K[p][k] = c * kp - s * kq; K[qq][k] = s * kp + c * kq;
            }
            for (int k = 0; k < 3; ++k) {
                double vp = V[k][p], vq = V[k][qq];
                V[k][p] = c * vp - s * vq; V[k][qq] = s * vp + c * vq;
            }
        }
    }
    double lam[3] = {K[0][0], K[1][1], K[2][2]};
    for (int i = 0; i < 2; ++i)
        for (int j = i + 1; j < 3; ++j)
            if (lam[j] > lam[i]) {
                double tmp = lam[i]; lam[i] = lam[j]; lam[j] = tmp;
                for (int k = 0; k < 3; ++k) {
                    double tv = V[k][i]; V[k][i] = V[k][j]; V[k][j] = tv;
                }
            }
    double U[3][3], sig[3];
    for (int k = 0; k < 3; ++k) {
        double u0 = H[0][0] * V[0][k] + H[0][1] * V[1][k] + H[0][2] * V[2][k];
        double u1 = H[1][0] * V[0][k] + H[1][1] * V[1][k] + H[1][2] * V[2][k];
        double u2 = H[2][0] * V[0][k] + H[2][1] * V[1][k] + H[2][2] * V[2][k];
        double nrm = sqrt(u0 * u0 + u1 * u1 + u2 * u2);
        sig[k] = nrm;
        double inv = (nrm > 1e-30) ? 1.0 / nrm : 0.0;
        U[0][k] = u0 * inv; U[1][k] = u1 * inv; U[2][k] = u2 * inv;
    }
    if (sig[2] <= 1e-10 * fmax(sig[0], 1e-300)) {
        U[0][2] = U[1][0] * U[2][1] - U[2][0] * U[1][1];
        U[1][2] = U[2][0] * U[0][1] - U[0][0] * U[2][1];
        U[2][2] = U[0][0] * U[1][1] - U[1][0] * U[0][1];
    }
    {
        double d01 = U[0][1] * U[0][0] + U[1][1] * U[1][0] + U[2][1] * U[2][0];
        for (int i = 0; i < 3; ++i) U[i][1] -= d01 * U[i][0];
        double n1 = sqrt(U[0][1] * U[0][1] + U[1][1] * U[1][1] + U[2][1] * U[2][1]);
        if (n1 > 1e-30) for (int i = 0; i < 3; ++i) U[i][1] /= n1;
        double d02 = U[0][2] * U[0][0] + U[1][2] * U[1][0] + U[2][2] * U[2][0];
        double d12 = U[0][2] * U[0][1] + U[1][2] * U[1][1] + U[2][2] * U[2][1];
        for (int i = 0; i < 3; ++i) U[i][2] -= d02 * U[i][0] + d12 * U[i][1];
        double n2 = sqrt(U[0][2] * U[0][2] + U[1][2] * U[1][2] + U[2][2] * U[2][2]);
        if (n2 > 1e-30) for (int i = 0; i < 3; ++i) U[i][2] /= n2;
    }

    double detH =
        H[0][0] * (H[1][1] * H[2][2] - H[1][2] * H[2][1]) -
        H[0][1] * (H[1][0] * H[2][2] - H[1][2] * H[2][0]) +
        H[0][2] * (H[1][0] * H[2][1] - H[1][1] * H[2][0]);
    double s3 = (detH < 0.0) ? -1.0 : 1.0;

    double R[3][3];
    for (int i = 0; i < 3; ++i)
        for (int j = 0; j < 3; ++j)
            R[i][j] = V[i][0] * U[j][0] + V[i][1] * U[j][1] + s3 * V[i][2] * U[j][2];

    double tv[3];
    for (int i = 0; i < 3; ++i)
        tv[i] = cm[i] - (R[i][0] * am[0] + R[i][1] * am[1] + R[i][2] * am[2]);

    float* Rout = out + (size_t)b * 9;
    for (int i = 0; i < 3; ++i)
        for (int j = 0; j < 3; ++j)
            Rout[3 * i + j] = (float)R[i][j];
    float* Tout = out + 288 + (size_t)b * 3;
    for (int i = 0; i < 3; ++i) Tout[i] = (float)tv[i];
}

extern "C" void kernel_launch(void* const* d_in, const int* in_sizes, int n_in,
                              void* d_out, int out_size, void* d_ws, size_t ws_size,
                              hipStream_t stream) {
    (void)in_sizes; (void)n_in; (void)out_size; (void)ws_size;
    const float* AE  = (const float*)d_in[0];  // action_embedding [B,64,N]
    const float* KE  = (const float*)d_in[1];  // anchor_embedding [B,64,M]
    const float* ACP = (const float*)d_in[2];  // action_points    [B,3,N]
    const float* ANP = (const float*)d_in[3];  // anchor_points    [B,3,M]
    float* out = (float*)d_out;

    hfrag8* KH    = (hfrag8*)d_ws;                         // 8 MB fp16 frags
    facc4*  VP    = (facc4*)((char*)d_ws + (8u << 20));    // 1 MB packed V
    float*  PART  = (float*)((char*)d_ws + (10u << 20));   // 4 MB partials
    float*  PART2 = (float*)((char*)d_ws + (15u << 20));   // 16 KB stage-2 partials

    prep_k<<<dim3(MM / 64, BB), 256, 0, stream>>>(KE, ANP, KH, VP);
    attn_main<<<dim3(MSPLIT, NN / (32 * 4), BB), 256, 0, stream>>>(AE, VP, KH, PART);
    reduce_part<<<256, 256, 0, stream>>>(PART, ACP, PART2);
    svd_final<<<1, 64, 0, stream>>>(PART2, out);
}